// Round 2
// baseline (65.902 us; speedup 1.0000x reference)
//
#include <hip/hip_runtime.h>
#include <hip/hip_bf16.h>
#include <math.h>

// ---------------------------------------------------------------------------
// NTXentLoss fused, symmetric-triangle version.
// loss = mean(lse(logits) - picked), logits = (G G^T), G = sqrt(2)*f/||f||.
// S is symmetric => rowsum_i(exp) == colsum_i(exp).  Compute only tile-pairs
// (rb,cb) with cb<=rb (2080 blocks of 128x128); each off-diagonal tile
// contributes exp-row-sums to slot cb (rows of rb-panel) AND exp-col-sums to
// slot rb (rows of cb-panel).  partial[64][8192]: slot c / panel p is written
// by exactly one block (max(p,c),min(p,c)) -> deterministic, no atomics.
// ---------------------------------------------------------------------------

#define B_ROWS 4096
#define D_DIM  256
#define N_ROWS 8192
#define NPANEL 64            // 8192 / 128
#define NTRI   2080          // 64*65/2, = 8*260 (XCD-bijective)

typedef __attribute__((ext_vector_type(8))) short short8;
typedef __attribute__((ext_vector_type(4))) float f32x4;

__device__ __forceinline__ float bf2f(unsigned short u) {
  union { unsigned int i; float f; } p; p.i = ((unsigned int)u) << 16; return p.f;
}

// ---------------- kernel 1: fp32 -> normalized bf16 rows -------------------
__global__ __launch_bounds__(256) void nt_normalize(const float* __restrict__ f1,
                                                    const float* __restrict__ f2,
                                                    unsigned short* __restrict__ G) {
  const int row  = blockIdx.x * 4 + (threadIdx.x >> 6);
  const int lane = threadIdx.x & 63;
  const float* src = (row < B_ROWS) ? (f1 + (size_t)row * D_DIM)
                                    : (f2 + (size_t)(row - B_ROWS) * D_DIM);
  float4 v = reinterpret_cast<const float4*>(src)[lane];
  float ss = v.x * v.x + v.y * v.y + v.z * v.z + v.w * v.w;
#pragma unroll
  for (int m = 1; m < 64; m <<= 1) ss += __shfl_xor(ss, m, 64);
  float scale = 1.41421356237309515f * rsqrtf(fmaxf(ss, 1e-30f));
  union { ushort4 u; __hip_bfloat16 h[4]; } p;
  p.h[0] = __float2bfloat16(v.x * scale);
  p.h[1] = __float2bfloat16(v.y * scale);
  p.h[2] = __float2bfloat16(v.z * scale);
  p.h[3] = __float2bfloat16(v.w * scale);
  reinterpret_cast<ushort4*>(G + (size_t)row * D_DIM)[lane] = p.u;
}

// ---------------- kernel 2: picked[i] = dot(g_i, g_label(i)) ---------------
__global__ __launch_bounds__(256) void nt_picked(const unsigned short* __restrict__ G,
                                                 float* __restrict__ picked) {
  const int row  = blockIdx.x * 4 + (threadIdx.x >> 6);
  const int lane = threadIdx.x & 63;
  const int lbl  = (row < B_ROWS) ? row : (row - B_ROWS);
  ushort4 a = reinterpret_cast<const ushort4*>(G + (size_t)row * D_DIM)[lane];
  ushort4 b = reinterpret_cast<const ushort4*>(G + (size_t)lbl * D_DIM)[lane];
  float s = bf2f(a.x) * bf2f(b.x) + bf2f(a.y) * bf2f(b.y) +
            bf2f(a.z) * bf2f(b.z) + bf2f(a.w) * bf2f(b.w);
#pragma unroll
  for (int m = 1; m < 64; m <<= 1) s += __shfl_xor(s, m, 64);
  if (lane == 0) picked[row] = s;
}

// ------------- staging helper: contiguous global -> LDS, swizzled ----------
// LDS[o] = G[base + swz(o)], swz(o) = o ^ (((o>>9)&7)<<4)  (row stride 512 B).
__device__ __forceinline__ void stage_lds(const char* gsrc_base, char* lds_base,
                                          int rounds, int tid) {
  const int lane = tid & 63, wid = tid >> 6;
  for (int r = 0; r < rounds; ++r) {
    const int o  = r * 4096 + wid * 1024 + lane * 16;
    const int so = o ^ (((o >> 9) & 7) << 4);
    __builtin_amdgcn_global_load_lds(
        (const __attribute__((address_space(1))) void*)(gsrc_base + so),
        (__attribute__((address_space(3))) void*)(lds_base + r * 4096 + wid * 1024),
        16, 0, 0);
  }
}

// -------- kernel 3: triangular GEMM tile-pair + fused exp row/col sums -----
// block = 256 thr (4 waves, 2x2), wave tile 64x64, tile 128x128.
// A panel (rb) -> registers; B panel (cb) staged in 64 KB LDS (swizzled).
__global__ __launch_bounds__(256, 2) void nt_gemm_tri(
    const unsigned short* __restrict__ G,
    float* __restrict__ partial)   // [NPANEL][N_ROWS]
{
  // XCD-contiguous remap (bijective: NTRI = 8*260), then triangular decode.
  int bid = (blockIdx.x & 7) * (NTRI / 8) + (blockIdx.x >> 3);
  int rb = (int)((sqrtf(8.f * (float)bid + 1.f) - 1.f) * 0.5f);
  while ((rb + 1) * (rb + 2) / 2 <= bid) ++rb;
  while (rb * (rb + 1) / 2 > bid) --rb;
  const int cb = bid - rb * (rb + 1) / 2;

  const int tid  = threadIdx.x;
  const int lane = tid & 63;
  const int wid  = tid >> 6;
  const int wr   = wid >> 1;          // row half (64 rows)
  const int wc   = wid & 1;           // col half (64 cols)

  __shared__ short8 lds8[4096];       // 64 KB
  char* ldsb = reinterpret_cast<char*>(lds8);
  const char* gb = reinterpret_cast<const char*>(G);

  // ---- stage A panel (rows rb*128..+128, 64 KB) ----
  stage_lds(gb + (size_t)rb * 128 * 512, ldsb, 16, tid);
  __syncthreads();

  // ---- A fragments -> registers ----
  short8 afrag[4][8];
  {
    const int r0 = wr * 64;
#pragma unroll
    for (int m = 0; m < 4; ++m) {
      const int row = r0 + m * 16 + (lane & 15);
      const int sw  = (row & 7) << 4;
#pragma unroll
      for (int ks = 0; ks < 8; ++ks) {
        const int off = (row * 512 + ks * 64 + ((lane >> 4) << 4)) ^ sw;
        afrag[m][ks] = *reinterpret_cast<const short8*>(ldsb + off);
      }
    }
  }
  __syncthreads();   // afrag reads done before B staging overwrites LDS

  // ---- stage B panel (rows cb*128..+128) into same LDS ----
  stage_lds(gb + (size_t)cb * 128 * 512, ldsb, 16, tid);
  f32x4 acc[4][4] = {};
  __syncthreads();

  // ---- K loop (fully unrolled, K = 256 = 8 * 32) ----
#pragma unroll
  for (int ks = 0; ks < 8; ++ks) {
    short8 bfrag[4];
#pragma unroll
    for (int n = 0; n < 4; ++n) {
      const int brow = wc * 64 + n * 16 + (lane & 15);   // tile-local col
      const int off  = (brow * 512 + ks * 64 + ((lane >> 4) << 4)) ^ ((brow & 7) << 4);
      bfrag[n] = *reinterpret_cast<const short8*>(ldsb + off);
    }
#pragma unroll
    for (int m = 0; m < 4; ++m)
#pragma unroll
      for (int n = 0; n < 4; ++n)
        acc[m][n] = __builtin_amdgcn_mfma_f32_16x16x32_bf16(
            afrag[m][ks], bfrag[n], acc[m][n], 0, 0, 0);
  }

  // ---- epilogue: exp, row sums (over cols) and col sums (over rows) ----
  // acc[m][n][j] is S at row wr*64+m*16+(lane>>4)*4+j, col wc*64+n*16+(lane&15)
  float rs[16], cs[4];
#pragma unroll
  for (int i = 0; i < 16; ++i) rs[i] = 0.f;
#pragma unroll
  for (int n = 0; n < 4; ++n) cs[n] = 0.f;
#pragma unroll
  for (int m = 0; m < 4; ++m)
#pragma unroll
    for (int n = 0; n < 4; ++n)
#pragma unroll
      for (int j = 0; j < 4; ++j) {
        const float e = __expf(acc[m][n][j]);
        rs[m * 4 + j] += e;
        cs[n] += e;
      }
  // rows: lanes sharing (lane>>4) hold same rows, different cols -> xor over &15
#pragma unroll
  for (int i = 0; i < 16; ++i) {
    float s = rs[i];
    s += __shfl_xor(s, 1, 64);
    s += __shfl_xor(s, 2, 64);
    s += __shfl_xor(s, 4, 64);
    s += __shfl_xor(s, 8, 64);
    rs[i] = s;
  }
  // cols: lanes sharing (lane&15) hold same cols, different rows -> xor 16,32
#pragma unroll
  for (int n = 0; n < 4; ++n) {
    float s = cs[n];
    s += __shfl_xor(s, 16, 64);
    s += __shfl_xor(s, 32, 64);
    cs[n] = s;
  }
  __syncthreads();   // LDS free for reductions
  float* redr = reinterpret_cast<float*>(ldsb);          // [2(wc)][128]
  float* redc = reinterpret_cast<float*>(ldsb + 1024);   // [2(wr)][128]
  if ((lane & 15) == 0) {
    const int g = lane >> 4;
#pragma unroll
    for (int i = 0; i < 16; ++i)
      redr[wc * 128 + wr * 64 + (i >> 2) * 16 + g * 4 + (i & 3)] = rs[i];
  }
  if ((lane >> 4) == 0) {
#pragma unroll
    for (int n = 0; n < 4; ++n)
      redc[wr * 128 + wc * 64 + n * 16 + lane] = cs[n];
  }
  __syncthreads();
  if (tid < 128) {
    const float v = redr[tid] + redr[128 + tid];
    partial[(size_t)cb * N_ROWS + (size_t)rb * 128 + tid] = v;
  } else if (rb != cb) {
    const int t = tid - 128;
    const float v = redc[t] + redc[128 + t];
    partial[(size_t)rb * N_ROWS + (size_t)cb * 128 + t] = v;
  }
}

// ------------- kernel 4a: per-128-row loss partials ------------------------
__global__ __launch_bounds__(128) void nt_finalize1(const float* __restrict__ partial,
                                                    const float* __restrict__ picked,
                                                    float* __restrict__ loss_part) {
  const int b = blockIdx.x, tid = threadIdx.x;
  const int r = b * 128 + tid;
  float s = 0.f;
#pragma unroll
  for (int c = 0; c < NPANEL; ++c) s += partial[(size_t)c * N_ROWS + r];
  float local = __logf(s) - picked[r];
#pragma unroll
  for (int m = 1; m < 64; m <<= 1) local += __shfl_xor(local, m, 64);
  __shared__ float red[2];
  if ((tid & 63) == 0) red[tid >> 6] = local;
  __syncthreads();
  if (tid == 0) loss_part[b] = red[0] + red[1];
}

// ------------- kernel 4b: final mean ---------------------------------------
__global__ __launch_bounds__(64) void nt_finalize2(const float* __restrict__ loss_part,
                                                   float* __restrict__ out) {
  const int tid = threadIdx.x;
  float v = loss_part[tid];
#pragma unroll
  for (int m = 1; m < 64; m <<= 1) v += __shfl_xor(v, m, 64);
  if (tid == 0) out[0] = v / (float)N_ROWS;
}

// ---------------------------------------------------------------------------
extern "C" void kernel_launch(void* const* d_in, const int* in_sizes, int n_in,
                              void* d_out, int out_size, void* d_ws, size_t ws_size,
                              hipStream_t stream) {
  const float* f1 = (const float*)d_in[0];
  const float* f2 = (const float*)d_in[1];
  float* out = (float*)d_out;

  char* ws = (char*)d_ws;
  unsigned short* G = (unsigned short*)ws;                              // 4 MB
  float* partial   = (float*)(ws + (size_t)4 * 1024 * 1024);            // 2 MB
  float* picked    = (float*)(ws + (size_t)6 * 1024 * 1024);            // 32 KB
  float* loss_part = (float*)(ws + (size_t)6 * 1024 * 1024 + 32 * 1024);// 256 B

  hipLaunchKernelGGL(nt_normalize, dim3(N_ROWS / 4), dim3(256), 0, stream, f1, f2, G);
  hipLaunchKernelGGL(nt_picked,    dim3(N_ROWS / 4), dim3(256), 0, stream, G, picked);
  hipLaunchKernelGGL(nt_gemm_tri,  dim3(NTRI),       dim3(256), 0, stream, G, partial);
  hipLaunchKernelGGL(nt_finalize1, dim3(NPANEL),     dim3(128), 0, stream, partial, picked, loss_part);
  hipLaunchKernelGGL(nt_finalize2, dim3(1),          dim3(64),  0, stream, loss_part, out);
}